// Round 1
// baseline (84.015 us; speedup 1.0000x reference)
//
#include <hip/hip_runtime.h>
#include <math.h>

typedef float v2f __attribute__((ext_vector_type(2)));

#define N_BOX   256
#define M_PTS   512
#define S_SPLIT 8                    // m2-range splits per box
#define BLK_B   256                  // 4 waves per block
#define M2_PER  (M_PTS / S_SPLIT)    // 64 m2 per block
#define GRID_B  (N_BOX * S_SPLIT)    // 2048 blocks -> 8192 waves = 32 waves/CU

// ws layout:
//   [0, 2MB)      P1: float4 per (n,m) = {Gx*rs+px*rs, Gy*rs+py*rs, gvx, gvy}
//   [2MB, 4MB)    P2: float4 per (n,m) = {mx*rs, my*rs, gvx*B, gvy*B}
//   [4MB, +8KB)   part: 2048 float partials

// ---- Kernel A: per-(box, point) geometry precompute. One block per box,
// one thread per mask point. Removes the per-split redundant phase-1 work
// that previously pinned the grid at 2 waves/SIMD. ----
__global__ __launch_bounds__(512) void precompute(
    const float* __restrict__ pred,    // (N,5)
    const float* __restrict__ target,  // (N,5)
    const float* __restrict__ mask,    // (N,M,2)
    const float* __restrict__ gradx,   // (N,M)
    const float* __restrict__ grady,   // (N,M)
    const float* __restrict__ offset,  // (N,2)
    float4* __restrict__ P1,
    float4* __restrict__ P2)
{
    const int n = blockIdx.x;
    const int m = threadIdx.x;

    // box scalars (uniform; redundantly computed per thread — cheap)
    const float offx = offset[n * 2 + 0];
    const float offy = offset[n * 2 + 1];
    const float px = pred[n * 5 + 0] - offx;
    const float py = pred[n * 5 + 1] - offy;
    const float pw = pred[n * 5 + 2];
    const float ph = pred[n * 5 + 3];
    const float pa = pred[n * 5 + 4];
    const float gx = target[n * 5 + 0] - offx;
    const float gy = target[n * 5 + 1] - offy;
    const float gw = target[n * 5 + 2];
    const float gh = target[n * 5 + 3];
    const float ga = target[n * 5 + 4];

    float sinpa, cospa, singa, cosga;
    sincosf(pa, &sinpa, &cospa);
    sincosf(ga, &singa, &cosga);

    const float THETA2   = 400.0f;
    const float LOG2E    = 1.4426950408889634f;
    const float c1       = LOG2E / (2.0f * THETA2 * THETA2);
    const float rs       = sqrtf(c1);
    const float inv_norm = 1.0f / (2.0f * (float)M_PI * THETA2);

    const float pwg = pw / gw, phg = ph / gh;
    const float cwx = pwg * cospa, swx = pwg * sinpa;
    const float chx = phg * cospa, shx = phg * sinpa;
    const float absinga = fabsf(singa);
    const float kA  = 15.0f * LOG2E / gw;
    const float kH  = 15.0f * LOG2E / gh;
    const float kB  = 15.0f * LOG2E;
    const float pxrs = px * rs, pyrs = py * rs;
    const bool  gaPos = (ga > 0.0f), gaNeg = (ga < 0.0f);

    const float2* mask2 = (const float2*)mask;
    const size_t  idx   = (size_t)n * M_PTS + m;

    const float2 mp = mask2[idx];
    const float dx = mp.x - gx;
    const float dy = mp.y - gy;
    // u = d*cos(beta), v = d*sin(beta) via rotation identity (no acos/sincos)
    const float u = singa * dy - cosga * dx;
    const float v = -(cosga * dy + singa * dx);
    const bool sgaOk = gaPos ? (dy <= 0.0f) : (gaNeg ? (dy > 0.0f) : false);
    const bool wrap  = sgaOk && (dx > 0.0f) && (dx * absinga > fabsf(dy) * cosga);
    const float au = fabsf(u), av = fabsf(v);            // d_w, d_h
    const float dws = (wrap || v > 0.0f) ? -au : au;
    const float dhs = (wrap || u > 0.0f) ? -av : av;
    const float gpx = dws * cwx - dhs * shx;
    const float gpy = dws * swx + dhs * chx;
    const float gvx = gradx[idx];
    const float gvy = grady[idx];

    // (1-sig(x))(1-sig(y)) = 1/((1+e^x)(1+e^y)), folded with 1/(2*pi*theta2)
    const float eA = __builtin_amdgcn_exp2f(fmaf(au, kA, -kB));
    const float eB = __builtin_amdgcn_exp2f(fmaf(av, kH, -kB));
    const float B  = inv_norm / ((1.0f + eA) * (1.0f + eB));

    P1[idx] = make_float4(fmaf(gpx, rs, pxrs), fmaf(gpy, rs, pyrs), gvx, gvy);
    P2[idx] = make_float4(mp.x * rs, mp.y * rs, gvx * B, gvy * B);
}

// ---- Kernel B: the O(N*M*M) pair loop at full occupancy.
// Block = (box n, m2 slice s). Thread t owns m1 rows {t, t+256} (v2f lanes).
// 32 waves/CU vs previous 8. ----
__global__ __launch_bounds__(BLK_B, 8) void pair_sum(
    const float4* __restrict__ P1,
    const float4* __restrict__ P2,
    float* __restrict__ part)
{
    __shared__ float4 sP[M2_PER];
    const int n = blockIdx.x >> 3;
    const int s = blockIdx.x & 7;
    const int t = threadIdx.x;

    const size_t base = (size_t)n * M_PTS;
    if (t < M2_PER) sP[t] = P2[base + s * M2_PER + t];

    const float4 g0 = P1[base + t];
    const float4 g1 = P1[base + t + 256];
    __syncthreads();

    v2f Gx = {g0.x, g1.x};
    v2f Gy = {g0.y, g1.y};
    v2f accz = (v2f)0.0f, accw = (v2f)0.0f;

#pragma unroll 4
    for (int m2 = 0; m2 < M2_PER; ++m2) {
        const float4 p = sP[m2];          // broadcast ds_read_b128
        v2f dgx = Gx - p.x;
        v2f dgy = Gy - p.y;
        v2f sa  = dgx * dgx + dgy * dgy;  // pre-scaled by c1 via rs folding
        v2f e;
        e.x = __builtin_amdgcn_exp2f(sa.x);
        e.y = __builtin_amdgcn_exp2f(sa.y);
        accz += e * p.z;
        accw += e * p.w;
    }

    // sum w*e = gvx1*sum(zB*e) + gvy1*sum(wB*e)
    v2f gvx = {g0.z, g1.z};
    v2f gvy = {g0.w, g1.w};
    v2f tot = accz * gvx + accw * gvy;
    float acc = tot.x + tot.y;

#pragma unroll
    for (int off = 32; off > 0; off >>= 1)
        acc += __shfl_down(acc, off, 64);

    __shared__ float sW[4];
    if ((t & 63) == 0) sW[t >> 6] = acc;
    __syncthreads();
    if (t == 0) part[blockIdx.x] = sW[0] + sW[1] + sW[2] + sW[3];
}

// ---- Kernel C: final reduce of 2048 partials ----
__global__ __launch_bounds__(256) void loss_reduce(const float* __restrict__ part,
                                                   float* __restrict__ out)
{
    __shared__ float sW[4];
    const int t = threadIdx.x;
    const float4* p4 = (const float4*)part;            // 2048 floats = 512 float4
    const float4 a = p4[t];
    const float4 b = p4[t + 256];
    float acc = ((a.x + a.y) + (a.z + a.w)) + ((b.x + b.y) + (b.z + b.w));
#pragma unroll
    for (int off = 32; off > 0; off >>= 1)
        acc += __shfl_down(acc, off, 64);
    if ((t & 63) == 0) sW[t >> 6] = acc;
    __syncthreads();
    if (t == 0) {
        const float scale = 1.0f / ((float)N_BOX * (float)M_PTS * (float)M_PTS);
        out[0] = (sW[0] + sW[1] + sW[2] + sW[3]) * scale;
    }
}

extern "C" void kernel_launch(void* const* d_in, const int* in_sizes, int n_in,
                              void* d_out, int out_size, void* d_ws, size_t ws_size,
                              hipStream_t stream) {
    const float* pred   = (const float*)d_in[0];
    const float* target = (const float*)d_in[1];
    const float* mask   = (const float*)d_in[2];
    const float* gradx  = (const float*)d_in[3];
    const float* grady  = (const float*)d_in[4];
    const float* offset = (const float*)d_in[5];
    float* out = (float*)d_out;

    float4* P1  = (float4*)d_ws;                              // 2 MB
    float4* P2  = (float4*)((char*)d_ws + (2u << 20));        // 2 MB
    float*  part = (float*)((char*)d_ws + (4u << 20));        // 8 KB

    hipLaunchKernelGGL(precompute, dim3(N_BOX), dim3(M_PTS), 0, stream,
                       pred, target, mask, gradx, grady, offset, P1, P2);
    hipLaunchKernelGGL(pair_sum, dim3(GRID_B), dim3(BLK_B), 0, stream,
                       P1, P2, part);
    hipLaunchKernelGGL(loss_reduce, dim3(1), dim3(256), 0, stream, part, out);
}